// Round 1
// baseline (485.916 us; speedup 1.0000x reference)
//
#include <hip/hip_runtime.h>

#define H_ 32
#define E_ 32
#define C_ 1024
#define L_ 1024
#define N_ 4
#define M_ 4096      // N_*L_
#define NH_ 128      // N_*H_
#define D_ 257
#define TEMP_ 0.17677669529663687f

typedef unsigned short u16;
typedef __attribute__((ext_vector_type(8))) short short8;
typedef __attribute__((ext_vector_type(4))) float f32x4;
typedef __attribute__((ext_vector_type(4))) unsigned short u16x4;

__device__ __forceinline__ u16 f2bf(float f) {
  union { float f; unsigned u; } v; v.f = f;
  unsigned r = v.u + 0x7fffu + ((v.u >> 16) & 1u);
  return (u16)(r >> 16);
}
__device__ __forceinline__ float bf2f(u16 h) {
  union { unsigned u; float f; } v; v.u = ((unsigned)h) << 16;
  return v.f;
}
__device__ __forceinline__ f32x4 mfma16(short8 a, short8 b, f32x4 c) {
  return __builtin_amdgcn_mfma_f32_16x16x32_bf16(a, b, c, 0, 0, 0);
}

// ---- prep: dist_emb -> bf16, pack qkv bias ----
__global__ __launch_bounds__(256) void prep_kernel(
    const float* __restrict__ demb, const float* __restrict__ bq,
    const float* __restrict__ bk, const float* __restrict__ bv,
    u16* __restrict__ demb_b, float* __restrict__ bqkv) {
  int i = blockIdx.x * 256 + threadIdx.x;
  if (i < D_ * E_) demb_b[i] = f2bf(demb[i]);
  if (i < C_) { bqkv[i] = bq[i]; bqkv[C_ + i] = bk[i]; bqkv[2 * C_ + i] = bv[i]; }
}

// ---- x (fp32) -> bf16 ----
__global__ __launch_bounds__(256) void cvt_x_kernel(const float* __restrict__ x,
                                                    u16* __restrict__ xb) {
  int i = blockIdx.x * 256 + threadIdx.x;
  f32x4 v = reinterpret_cast<const f32x4*>(x)[i];
  u16x4 o2;
  o2[0] = f2bf(v[0]); o2[1] = f2bf(v[1]); o2[2] = f2bf(v[2]); o2[3] = f2bf(v[3]);
  reinterpret_cast<u16x4*>(xb)[i] = o2;
}

// ---- W (K x N, fp32) -> W^T (N x K, bf16), LDS-tiled transpose ----
__global__ __launch_bounds__(256) void transpose_w_kernel(const float* __restrict__ in,
                                                          u16* __restrict__ out) {
  __shared__ float tile[32][33];
  int j0 = blockIdx.x * 32, c0 = blockIdx.y * 32;
#pragma unroll
  for (int i = 0; i < 4; ++i) {
    int cy = threadIdx.y + i * 8;
    tile[cy][threadIdx.x] = in[(size_t)(c0 + cy) * C_ + j0 + threadIdx.x];
  }
  __syncthreads();
#pragma unroll
  for (int i = 0; i < 4; ++i) {
    int jy = threadIdx.y + i * 8;
    out[(size_t)(j0 + jy) * C_ + c0 + threadIdx.x] = f2bf(tile[threadIdx.x][jy]);
  }
}

// ---- GEMM: C[M x Ncols] = A[M x K] * Bt[Ncols x K]^T, bf16 in / fp32 acc ----
// EPI 0: +bqkv, scatter q (N,H,L,E), k (N,H,L,E), vT (N,H,E,L) bf16
// EPI 1: +bias, relu, bf16 row-major
// EPI 2: +bias, bf16 row-major
template <int EPI>
__global__ __launch_bounds__(256) void gemm128_kernel(
    const u16* __restrict__ A, const u16* __restrict__ Bt, int K,
    const float* __restrict__ bias,
    u16* __restrict__ out0, u16* __restrict__ out1, u16* __restrict__ out2) {
  __shared__ u16 As[128 * 64];
  __shared__ u16 Bs[128 * 64];
  const int bid = blockIdx.x;
  const int m0 = (bid & 31) << 7;
  const int n0 = (bid >> 5) << 7;
  const int tid = threadIdx.x;
  const int w = tid >> 6, lane = tid & 63, lhi = lane >> 4, llo = lane & 15;
  const int wr = w >> 1, wc = w & 1;
  f32x4 acc[4][4] = {};
  for (int k0 = 0; k0 < K; k0 += 64) {
#pragma unroll
    for (int i = 0; i < 4; ++i) {
      int e = i * 256 + tid;
      int row = e >> 3, c8 = (e & 7) << 3;
      *reinterpret_cast<short8*>(&As[row * 64 + c8]) =
          *reinterpret_cast<const short8*>(&A[(size_t)(m0 + row) * K + k0 + c8]);
      *reinterpret_cast<short8*>(&Bs[row * 64 + c8]) =
          *reinterpret_cast<const short8*>(&Bt[(size_t)(n0 + row) * K + k0 + c8]);
    }
    __syncthreads();
#pragma unroll
    for (int kk = 0; kk < 2; ++kk) {
      const int ko = (kk << 5) + lhi * 8;
      short8 af[4], bf[4];
#pragma unroll
      for (int mi = 0; mi < 4; ++mi)
        af[mi] = *reinterpret_cast<const short8*>(&As[(wr * 64 + mi * 16 + llo) * 64 + ko]);
#pragma unroll
      for (int ni = 0; ni < 4; ++ni)
        bf[ni] = *reinterpret_cast<const short8*>(&Bs[(wc * 64 + ni * 16 + llo) * 64 + ko]);
#pragma unroll
      for (int mi = 0; mi < 4; ++mi)
#pragma unroll
        for (int ni = 0; ni < 4; ++ni)
          acc[mi][ni] = mfma16(af[mi], bf[ni], acc[mi][ni]);
    }
    __syncthreads();
  }
#pragma unroll
  for (int mi = 0; mi < 4; ++mi)
#pragma unroll
    for (int ni = 0; ni < 4; ++ni)
#pragma unroll
      for (int r = 0; r < 4; ++r) {
        int row = m0 + wr * 64 + mi * 16 + lhi * 4 + r;
        int col = n0 + wc * 64 + ni * 16 + llo;
        float v = acc[mi][ni][r] + bias[col];
        if constexpr (EPI == 0) {
          int which = col >> 10, jj = col & 1023, h = jj >> 5, e2 = jj & 31;
          int n = row >> 10, l = row & 1023;
          int nh = (n << 5) | h;
          u16 bvv = f2bf(v);
          if (which == 0)      out0[((size_t)((nh << 10) | l)) * 32 + e2] = bvv;
          else if (which == 1) out1[((size_t)((nh << 10) | l)) * 32 + e2] = bvv;
          else                 out2[(((size_t)(nh * 32 + e2)) << 10) | l] = bvv;
        } else if constexpr (EPI == 1) {
          out0[(size_t)row * C_ + col] = f2bf(fmaxf(v, 0.f));
        } else {
          out0[(size_t)row * C_ + col] = f2bf(v);
        }
      }
}

// ---- QD/KD: dst[m, d] = sum_e src[m, e] * demb[d, e], 1 wave per 16 rows ----
__global__ __launch_bounds__(256) void qdkd_kernel(
    const u16* __restrict__ src, const u16* __restrict__ demb, u16* __restrict__ dst) {
  const int wt = blockIdx.x * 4 + (threadIdx.x >> 6);
  const int lane = threadIdx.x & 63, lhi = lane >> 4, llo = lane & 15;
  const int m0 = wt << 4;
  short8 a = *reinterpret_cast<const short8*>(&src[(size_t)(m0 + llo) * E_ + lhi * 8]);
#pragma unroll
  for (int ct = 0; ct < 17; ++ct) {
    int d = ct * 16 + llo;
    short8 b = {0, 0, 0, 0, 0, 0, 0, 0};
    if (d < D_) b = *reinterpret_cast<const short8*>(&demb[d * E_ + lhi * 8]);
    f32x4 c = {};
    c = mfma16(a, b, c);
    if (d < D_) {
#pragma unroll
      for (int r = 0; r < 4; ++r)
        dst[(size_t)(m0 + lhi * 4 + r) * D_ + d] = f2bf(c[r]);
    }
  }
}

// ---- attention: 1 WG = (n,h, 32 q-rows); S rows in LDS, exact softmax ----
__global__ __launch_bounds__(256) void attn_kernel(
    const u16* __restrict__ qw, const u16* __restrict__ kw,
    const u16* __restrict__ vT, const u16* __restrict__ qd,
    const u16* __restrict__ kd, u16* __restrict__ tb) {
  __shared__ float S[32 * 1028];  // stride 1028 -> conflict-light
  const int bid = blockIdx.x;
  const int nh = bid >> 5;
  const int l0 = (bid & 31) << 5;
  const int tid = threadIdx.x;
  const int w = tid >> 6, lane = tid & 63, lhi = lane >> 4, llo = lane & 15;

  const u16* qb = qw + (size_t)nh * (L_ * E_);
  const u16* kb = kw + (size_t)nh * (L_ * E_);
  const u16* vb = vT + (size_t)nh * (E_ * L_);
  const u16* qdb = qd + (size_t)nh * ((size_t)L_ * D_);
  const u16* kdb = kd + (size_t)nh * ((size_t)L_ * D_);

  short8 aq0 = *reinterpret_cast<const short8*>(&qb[(l0 + llo) * E_ + lhi * 8]);
  short8 aq1 = *reinterpret_cast<const short8*>(&qb[(l0 + 16 + llo) * E_ + lhi * 8]);

  // phase 1: scores (each wave owns 16 s-columns per 64-wide s-tile)
  for (int st = 0; st < 16; ++st) {
    const int s0 = st * 64 + w * 16;
    short8 bk_ = *reinterpret_cast<const short8*>(&kb[(s0 + llo) * E_ + lhi * 8]);
    f32x4 acc0 = {}, acc1 = {};
    acc0 = mfma16(aq0, bk_, acc0);
    acc1 = mfma16(aq1, bk_, acc1);
    const int scol = s0 + llo;
#pragma unroll
    for (int mi = 0; mi < 2; ++mi) {
#pragma unroll
      for (int r = 0; r < 4; ++r) {
        const int ll = mi * 16 + lhi * 4 + r;
        const int lg = l0 + ll;
        int dd = lg - scol;
        dd = dd < -128 ? 0 : (dd > 128 ? 256 : dd + 128);
        float val = (mi ? acc1[r] : acc0[r])
                  + bf2f(qdb[(size_t)lg * D_ + dd])
                  + bf2f(kdb[(size_t)scol * D_ + dd]);
        S[ll * 1028 + scol] = val * TEMP_;
      }
    }
  }
  __syncthreads();

  // phase 2: softmax, wave w -> rows [w*8, w*8+8)
#pragma unroll
  for (int i = 0; i < 8; ++i) {
    const int row = w * 8 + i;
    float v[16]; float mx = -3.0e38f;
#pragma unroll
    for (int j = 0; j < 16; ++j) { v[j] = S[row * 1028 + lane + j * 64]; mx = fmaxf(mx, v[j]); }
#pragma unroll
    for (int off = 32; off >= 1; off >>= 1) mx = fmaxf(mx, __shfl_xor(mx, off));
    float sum = 0.f;
#pragma unroll
    for (int j = 0; j < 16; ++j) { v[j] = __expf(v[j] - mx); sum += v[j]; }
#pragma unroll
    for (int off = 32; off >= 1; off >>= 1) sum += __shfl_xor(sum, off);
    const float inv = 1.f / sum;
#pragma unroll
    for (int j = 0; j < 16; ++j) S[row * 1028 + lane + j * 64] = v[j] * inv;
  }
  __syncthreads();

  // phase 3: O = P @ V, K-split across waves (wave w: s in [w*256, w*256+256))
  f32x4 o00 = {}, o01 = {}, o10 = {}, o11 = {};
  for (int ks = 0; ks < 8; ++ks) {
    const int k0 = w * 256 + ks * 32;
    const float* sp0 = &S[llo * 1028 + k0 + lhi * 8];
    const float* sp1 = &S[(16 + llo) * 1028 + k0 + lhi * 8];
    short8 pa0, pa1;
#pragma unroll
    for (int j = 0; j < 8; ++j) {
      pa0[j] = (short)f2bf(sp0[j]);
      pa1[j] = (short)f2bf(sp1[j]);
    }
    short8 bv0 = *reinterpret_cast<const short8*>(&vb[(size_t)llo * L_ + k0 + lhi * 8]);
    short8 bv1 = *reinterpret_cast<const short8*>(&vb[(size_t)(16 + llo) * L_ + k0 + lhi * 8]);
    o00 = mfma16(pa0, bv0, o00);
    o01 = mfma16(pa0, bv1, o01);
    o10 = mfma16(pa1, bv0, o10);
    o11 = mfma16(pa1, bv1, o11);
  }
  __syncthreads();
  // cross-wave reduce via LDS (reuse S)
  float* Op = &S[0];
#pragma unroll
  for (int r = 0; r < 4; ++r) {
    const int llr = lhi * 4 + r;
    Op[(w * 32 + llr) * 32 + llo] = o00[r];
    Op[(w * 32 + llr) * 32 + 16 + llo] = o01[r];
    Op[(w * 32 + 16 + llr) * 32 + llo] = o10[r];
    Op[(w * 32 + 16 + llr) * 32 + 16 + llo] = o11[r];
  }
  __syncthreads();
  const int n = nh >> 5, h = nh & 31;
#pragma unroll
  for (int i = 0; i < 4; ++i) {
    const int idx = i * 256 + tid;
    const int ll = idx >> 5, e = idx & 31;
    float sum = Op[idx] + Op[1024 + idx] + Op[2048 + idx] + Op[3072 + idx];
    tb[(((size_t)((n << 10) | (l0 + ll))) * 32 + h) * 32 + e] = f2bf(sum);
  }
}

// ---- AddNorm 1: h = LN(t + x) -> bf16 ----
__global__ __launch_bounds__(256) void ln1_kernel(
    const u16* __restrict__ tbuf, const float* __restrict__ x,
    const float* __restrict__ g, const float* __restrict__ b,
    u16* __restrict__ hb) {
  __shared__ float red[8];
  const int row = blockIdx.x, tid = threadIdx.x;
  const size_t base = (size_t)row * C_ + tid * 4;
  f32x4 xv = *reinterpret_cast<const f32x4*>(&x[base]);
  u16x4 tv = *reinterpret_cast<const u16x4*>(&tbuf[base]);
  float v[4]; float s1 = 0.f, s2 = 0.f;
#pragma unroll
  for (int i = 0; i < 4; ++i) {
    v[i] = xv[i] + bf2f(tv[i]);
    s1 += v[i]; s2 += v[i] * v[i];
  }
#pragma unroll
  for (int off = 32; off >= 1; off >>= 1) {
    s1 += __shfl_xor(s1, off); s2 += __shfl_xor(s2, off);
  }
  if ((tid & 63) == 0) { red[tid >> 6] = s1; red[4 + (tid >> 6)] = s2; }
  __syncthreads();
  float S1 = red[0] + red[1] + red[2] + red[3];
  float S2 = red[4] + red[5] + red[6] + red[7];
  float mu = S1 * (1.f / C_);
  float rs = rsqrtf(S2 * (1.f / C_) - mu * mu + 1e-5f);
#pragma unroll
  for (int i = 0; i < 4; ++i) {
    int c = tid * 4 + i;
    hb[base + i] = f2bf((v[i] - mu) * rs * g[c] + b[c]);
  }
}

// ---- AddNorm 2: out = LN(m + h) -> fp32, transposed (L, N, C) ----
__global__ __launch_bounds__(256) void ln2_kernel(
    const u16* __restrict__ mb, const u16* __restrict__ hb,
    const float* __restrict__ g, const float* __restrict__ b,
    float* __restrict__ out) {
  __shared__ float red[8];
  const int row = blockIdx.x, tid = threadIdx.x;
  const size_t base = (size_t)row * C_ + tid * 4;
  u16x4 mv = *reinterpret_cast<const u16x4*>(&mb[base]);
  u16x4 hv = *reinterpret_cast<const u16x4*>(&hb[base]);
  float v[4]; float s1 = 0.f, s2 = 0.f;
#pragma unroll
  for (int i = 0; i < 4; ++i) {
    v[i] = bf2f(mv[i]) + bf2f(hv[i]);
    s1 += v[i]; s2 += v[i] * v[i];
  }
#pragma unroll
  for (int off = 32; off >= 1; off >>= 1) {
    s1 += __shfl_xor(s1, off); s2 += __shfl_xor(s2, off);
  }
  if ((tid & 63) == 0) { red[tid >> 6] = s1; red[4 + (tid >> 6)] = s2; }
  __syncthreads();
  float S1 = red[0] + red[1] + red[2] + red[3];
  float S2 = red[4] + red[5] + red[6] + red[7];
  float mu = S1 * (1.f / C_);
  float rs = rsqrtf(S2 * (1.f / C_) - mu * mu + 1e-5f);
  const int n = row >> 10, l = row & 1023;
  const size_t ob = (size_t)(l * N_ + n) * C_ + tid * 4;
#pragma unroll
  for (int i = 0; i < 4; ++i) {
    int c = tid * 4 + i;
    out[ob + i] = (v[i] - mu) * rs * g[c] + b[c];
  }
}

extern "C" void kernel_launch(void* const* d_in, const int* in_sizes, int n_in,
                              void* d_out, int out_size, void* d_ws, size_t ws_size,
                              hipStream_t stream) {
  const float* x    = (const float*)d_in[0];
  const float* Wq   = (const float*)d_in[1];
  const float* bq   = (const float*)d_in[2];
  const float* Wk   = (const float*)d_in[3];
  const float* bk   = (const float*)d_in[4];
  const float* Wv   = (const float*)d_in[5];
  const float* bv   = (const float*)d_in[6];
  const float* demb = (const float*)d_in[7];
  const float* g1   = (const float*)d_in[8];
  const float* b1ln = (const float*)d_in[9];
  const float* g2   = (const float*)d_in[10];
  const float* b2ln = (const float*)d_in[11];
  const float* W1   = (const float*)d_in[12];
  const float* b1   = (const float*)d_in[13];
  const float* W2   = (const float*)d_in[14];
  const float* b2   = (const float*)d_in[15];
  float* outp = (float*)d_out;

  size_t o = 0;
  auto alloc = [&](size_t bytes) { size_t r = o; o += (bytes + 255) & ~(size_t)255; return r; };
  const size_t xb_o   = alloc((size_t)M_ * C_ * 2);
  const size_t wqkv_o = alloc((size_t)3 * C_ * C_ * 2);
  const size_t w1_o   = alloc((size_t)C_ * C_ * 2);
  const size_t w2_o   = alloc((size_t)C_ * C_ * 2);
  const size_t bqkv_o = alloc((size_t)3 * C_ * 4);
  const size_t demb_o = alloc((size_t)D_ * E_ * 2);
  const size_t q_o    = alloc((size_t)NH_ * L_ * E_ * 2);
  const size_t k_o    = alloc((size_t)NH_ * L_ * E_ * 2);
  const size_t vt_o   = alloc((size_t)NH_ * L_ * E_ * 2);
  const size_t qd_o   = alloc((size_t)NH_ * L_ * D_ * 2);
  const size_t kd_o   = alloc((size_t)NH_ * L_ * D_ * 2);
  const size_t t_o    = alloc((size_t)M_ * C_ * 2);
  const size_t h_o    = alloc((size_t)M_ * C_ * 2);
  const size_t m1_o   = alloc((size_t)M_ * C_ * 2);
  const size_t m_o    = alloc((size_t)M_ * C_ * 2);
  if (o > ws_size) return;  // ws too small -> visible zero-output failure

  char* ws = (char*)d_ws;
  u16*   xb     = (u16*)(ws + xb_o);
  u16*   wqkv_t = (u16*)(ws + wqkv_o);
  u16*   w1_t   = (u16*)(ws + w1_o);
  u16*   w2_t   = (u16*)(ws + w2_o);
  float* bqkv   = (float*)(ws + bqkv_o);
  u16*   demb_b = (u16*)(ws + demb_o);
  u16*   q_ws   = (u16*)(ws + q_o);
  u16*   k_ws   = (u16*)(ws + k_o);
  u16*   vT_ws  = (u16*)(ws + vt_o);
  u16*   QD     = (u16*)(ws + qd_o);
  u16*   KD     = (u16*)(ws + kd_o);
  u16*   t_b16  = (u16*)(ws + t_o);
  u16*   h_b16  = (u16*)(ws + h_o);
  u16*   m1_b16 = (u16*)(ws + m1_o);
  u16*   m_b16  = (u16*)(ws + m_o);

  prep_kernel<<<33, 256, 0, stream>>>(demb, bq, bk, bv, demb_b, bqkv);
  cvt_x_kernel<<<(M_ * C_) / 1024, 256, 0, stream>>>(x, xb);
  dim3 tb_(32, 8), tg_(32, 32);
  transpose_w_kernel<<<tg_, tb_, 0, stream>>>(Wq, wqkv_t);
  transpose_w_kernel<<<tg_, tb_, 0, stream>>>(Wk, wqkv_t + (size_t)C_ * C_);
  transpose_w_kernel<<<tg_, tb_, 0, stream>>>(Wv, wqkv_t + (size_t)2 * C_ * C_);
  transpose_w_kernel<<<tg_, tb_, 0, stream>>>(W1, w1_t);
  transpose_w_kernel<<<tg_, tb_, 0, stream>>>(W2, w2_t);

  gemm128_kernel<0><<<32 * 24, 256, 0, stream>>>(xb, wqkv_t, C_, bqkv, q_ws, k_ws, vT_ws);

  qdkd_kernel<<<2048, 256, 0, stream>>>(q_ws, demb_b, QD);
  qdkd_kernel<<<2048, 256, 0, stream>>>(k_ws, demb_b, KD);

  attn_kernel<<<NH_ * 32, 256, 0, stream>>>(q_ws, k_ws, vT_ws, QD, KD, t_b16);

  ln1_kernel<<<M_, 256, 0, stream>>>(t_b16, x, g1, b1ln, h_b16);

  gemm128_kernel<1><<<32 * 8, 256, 0, stream>>>(h_b16, w1_t, C_, b1, m1_b16, nullptr, nullptr);
  gemm128_kernel<2><<<32 * 8, 256, 0, stream>>>(m1_b16, w2_t, C_, b2, m_b16, nullptr, nullptr);

  ln2_kernel<<<M_, 256, 0, stream>>>(m_b16, h_b16, g2, b2ln, outp);
}

// Round 2
// 308.885 us; speedup vs baseline: 1.5731x; 1.5731x over previous
//
#include <hip/hip_runtime.h>

#define H_ 32
#define E_ 32
#define C_ 1024
#define L_ 1024
#define N_ 4
#define M_ 4096      // N_*L_
#define NH_ 128      // N_*H_
#define D_ 257
#define QDP 264      // padded QD row stride (16B-aligned rows, 2-way LDS banks)
#define TEMP_ 0.17677669529663687f

typedef unsigned short u16;
typedef __attribute__((ext_vector_type(8))) short short8;
typedef __attribute__((ext_vector_type(4))) float f32x4;
typedef __attribute__((ext_vector_type(4))) unsigned short u16x4;

__device__ __forceinline__ u16 f2bf(float f) {
  union { float f; unsigned u; } v; v.f = f;
  unsigned r = v.u + 0x7fffu + ((v.u >> 16) & 1u);
  return (u16)(r >> 16);
}
__device__ __forceinline__ float bf2f(u16 h) {
  union { unsigned u; float f; } v; v.u = ((unsigned)h) << 16;
  return v.f;
}
__device__ __forceinline__ f32x4 mfma16(short8 a, short8 b, f32x4 c) {
  return __builtin_amdgcn_mfma_f32_16x16x32_bf16(a, b, c, 0, 0, 0);
}

// ---- prep: dist_emb -> bf16, pack qkv bias ----
__global__ __launch_bounds__(256) void prep_kernel(
    const float* __restrict__ demb, const float* __restrict__ bq,
    const float* __restrict__ bk, const float* __restrict__ bv,
    u16* __restrict__ demb_b, float* __restrict__ bqkv) {
  int i = blockIdx.x * 256 + threadIdx.x;
  if (i < D_ * E_) demb_b[i] = f2bf(demb[i]);
  if (i < C_) { bqkv[i] = bq[i]; bqkv[C_ + i] = bk[i]; bqkv[2 * C_ + i] = bv[i]; }
}

// ---- x (fp32) -> bf16 ----
__global__ __launch_bounds__(256) void cvt_x_kernel(const float* __restrict__ x,
                                                    u16* __restrict__ xb) {
  int i = blockIdx.x * 256 + threadIdx.x;
  f32x4 v = reinterpret_cast<const f32x4*>(x)[i];
  u16x4 o2;
  o2[0] = f2bf(v[0]); o2[1] = f2bf(v[1]); o2[2] = f2bf(v[2]); o2[3] = f2bf(v[3]);
  reinterpret_cast<u16x4*>(xb)[i] = o2;
}

// ---- W (K x N, fp32) -> W^T (N x K, bf16), LDS-tiled transpose ----
__global__ __launch_bounds__(256) void transpose_w_kernel(const float* __restrict__ in,
                                                          u16* __restrict__ out) {
  __shared__ float tile[32][33];
  int j0 = blockIdx.x * 32, c0 = blockIdx.y * 32;
#pragma unroll
  for (int i = 0; i < 4; ++i) {
    int cy = threadIdx.y + i * 8;
    tile[cy][threadIdx.x] = in[(size_t)(c0 + cy) * C_ + j0 + threadIdx.x];
  }
  __syncthreads();
#pragma unroll
  for (int i = 0; i < 4; ++i) {
    int jy = threadIdx.y + i * 8;
    out[(size_t)(j0 + jy) * C_ + c0 + threadIdx.x] = f2bf(tile[threadIdx.x][jy]);
  }
}

// ---- GEMM: C[M x Ncols] = A[M x K] * Bt[Ncols x K]^T, bf16 in / fp32 acc ----
// EPI 0: +bqkv, scatter q*TEMP (N,H,L,E), k (N,H,L,E), vT (N,H,E,L) bf16
// EPI 1: +bias, relu, bf16 row-major
// EPI 2: +bias, bf16 row-major
template <int EPI>
__global__ __launch_bounds__(256) void gemm128_kernel(
    const u16* __restrict__ A, const u16* __restrict__ Bt, int K,
    const float* __restrict__ bias,
    u16* __restrict__ out0, u16* __restrict__ out1, u16* __restrict__ out2) {
  __shared__ u16 As[128 * 64];
  __shared__ u16 Bs[128 * 64];
  const int bid = blockIdx.x;
  const int m0 = (bid & 31) << 7;
  const int n0 = (bid >> 5) << 7;
  const int tid = threadIdx.x;
  const int w = tid >> 6, lane = tid & 63, lhi = lane >> 4, llo = lane & 15;
  const int wr = w >> 1, wc = w & 1;
  f32x4 acc[4][4] = {};
  for (int k0 = 0; k0 < K; k0 += 64) {
#pragma unroll
    for (int i = 0; i < 4; ++i) {
      int e = i * 256 + tid;
      int row = e >> 3, c8 = (e & 7) << 3;
      *reinterpret_cast<short8*>(&As[row * 64 + c8]) =
          *reinterpret_cast<const short8*>(&A[(size_t)(m0 + row) * K + k0 + c8]);
      *reinterpret_cast<short8*>(&Bs[row * 64 + c8]) =
          *reinterpret_cast<const short8*>(&Bt[(size_t)(n0 + row) * K + k0 + c8]);
    }
    __syncthreads();
#pragma unroll
    for (int kk = 0; kk < 2; ++kk) {
      const int ko = (kk << 5) + lhi * 8;
      short8 af[4], bf[4];
#pragma unroll
      for (int mi = 0; mi < 4; ++mi)
        af[mi] = *reinterpret_cast<const short8*>(&As[(wr * 64 + mi * 16 + llo) * 64 + ko]);
#pragma unroll
      for (int ni = 0; ni < 4; ++ni)
        bf[ni] = *reinterpret_cast<const short8*>(&Bs[(wc * 64 + ni * 16 + llo) * 64 + ko]);
#pragma unroll
      for (int mi = 0; mi < 4; ++mi)
#pragma unroll
        for (int ni = 0; ni < 4; ++ni)
          acc[mi][ni] = mfma16(af[mi], bf[ni], acc[mi][ni]);
    }
    __syncthreads();
  }
#pragma unroll
  for (int mi = 0; mi < 4; ++mi)
#pragma unroll
    for (int ni = 0; ni < 4; ++ni)
#pragma unroll
      for (int r = 0; r < 4; ++r) {
        int row = m0 + wr * 64 + mi * 16 + lhi * 4 + r;
        int col = n0 + wc * 64 + ni * 16 + llo;
        float v = acc[mi][ni][r] + bias[col];
        if constexpr (EPI == 0) {
          int which = col >> 10, jj = col & 1023, h = jj >> 5, e2 = jj & 31;
          int n = row >> 10, l = row & 1023;
          int nh = (n << 5) | h;
          if (which == 0) v *= TEMP_;   // fold softmax temperature into q
          u16 bvv = f2bf(v);
          if (which == 0)      out0[((size_t)((nh << 10) | l)) * 32 + e2] = bvv;
          else if (which == 1) out1[((size_t)((nh << 10) | l)) * 32 + e2] = bvv;
          else                 out2[(((size_t)(nh * 32 + e2)) << 10) | l] = bvv;
        } else if constexpr (EPI == 1) {
          out0[(size_t)row * C_ + col] = f2bf(fmaxf(v, 0.f));
        } else {
          out0[(size_t)row * C_ + col] = f2bf(v);
        }
      }
}

// ---- QD/KD: dst[m, d] = scale * sum_e src[m, e] * demb[d, e] ----
// dstride: row stride of dst. aux0/aux256 (optional): clamp-value vectors.
__global__ __launch_bounds__(256) void qdkd_kernel(
    const u16* __restrict__ src, const u16* __restrict__ demb,
    u16* __restrict__ dst, int dstride, float scale,
    u16* __restrict__ aux0, u16* __restrict__ aux256) {
  const int wt = blockIdx.x * 4 + (threadIdx.x >> 6);
  const int lane = threadIdx.x & 63, lhi = lane >> 4, llo = lane & 15;
  const int m0 = wt << 4;
  short8 a = *reinterpret_cast<const short8*>(&src[(size_t)(m0 + llo) * E_ + lhi * 8]);
#pragma unroll
  for (int ct = 0; ct < 17; ++ct) {
    int d = ct * 16 + llo;
    short8 b = {0, 0, 0, 0, 0, 0, 0, 0};
    if (d < D_) b = *reinterpret_cast<const short8*>(&demb[d * E_ + lhi * 8]);
    f32x4 c = {};
    c = mfma16(a, b, c);
    if (d < D_) {
#pragma unroll
      for (int r = 0; r < 4; ++r) {
        u16 val = f2bf(c[r] * scale);
        dst[(size_t)(m0 + lhi * 4 + r) * dstride + d] = val;
        if (aux0 != nullptr && d == 0)     aux0[m0 + lhi * 4 + r] = val;
        if (aux256 != nullptr && d == 256) aux256[m0 + lhi * 4 + r] = val;
      }
    }
  }
}

// ---- attention v2: streaming one-pass softmax (no max, no S matrix) ----
// grid: NH * 16 blocks; 4 waves; wave w owns q-rows [l0+16w, l0+16w+16).
// S^T fragment layout: D col (llo) = q-row, D row (lhi*4+r) = scol.
__global__ __launch_bounds__(256) void attn_kernel(
    const u16* __restrict__ qw, const u16* __restrict__ kw,
    const u16* __restrict__ vT, const u16* __restrict__ QDg,
    const u16* __restrict__ KDg, const u16* __restrict__ kd0a,
    const u16* __restrict__ kd256a, u16* __restrict__ tb) {
  __shared__ u16 QDs[64 * QDP];   // 33792 B: QD rows for this q-block
  __shared__ u16 kdc[2 * 1024];   // 4096 B: KD clamp vectors (dd=0 / dd=256)
  __shared__ u16 Pbuf[4 * 512];   // 4096 B: per-wave P round-trip (1KB each)
  const int bid = blockIdx.x;
  const int nh = bid >> 4;
  const int l0 = (bid & 15) << 6;
  const int tid = threadIdx.x;
  const int w = tid >> 6, lane = tid & 63, lhi = lane >> 4, llo = lane & 15;
  const int lw0 = l0 + (w << 4);
  const int lg = lw0 + llo;
  const int lrow = (w << 4) + llo;    // row index within QDs

  const u16* qb  = qw + (size_t)nh * (L_ * E_);
  const u16* kb  = kw + (size_t)nh * (L_ * E_);
  const u16* vb  = vT + (size_t)nh * (E_ * L_);
  const u16* qdg = QDg + (size_t)nh * ((size_t)L_ * QDP);
  const u16* kdg = KDg + (size_t)nh * ((size_t)L_ * D_);

  // ---- stage QD rows (cols 0..255 vectorized + col 256 tail) and kdc ----
  {
    const int rr = tid >> 5, cc = tid & 31;
#pragma unroll
    for (int g = 0; g < 8; ++g) {
      int row = g * 8 + rr;
      *reinterpret_cast<short8*>(&QDs[row * QDP + cc * 8]) =
          *reinterpret_cast<const short8*>(&qdg[(size_t)(l0 + row) * QDP + cc * 8]);
    }
    if (tid < 64) QDs[tid * QDP + 256] = qdg[(size_t)(l0 + tid) * QDP + 256];
    const int side = tid >> 7, off = (tid & 127) * 8;
    const u16* srcA = (side ? kd256a : kd0a) + (size_t)nh * L_ + off;
    *reinterpret_cast<short8*>(&kdc[side * 1024 + off]) =
        *reinterpret_cast<const short8*>(srcA);
  }
  __syncthreads();

  const short8 qB = *reinterpret_cast<const short8*>(&qb[(size_t)lg * E_ + lhi * 8]);
  const float qd0   = bf2f(QDs[lrow * QDP + 0]);
  const float qd256 = bf2f(QDs[lrow * QDP + 256]);

  f32x4 o0 = {}, o1 = {};
  float l_acc = 0.f;
  char* Pw = reinterpret_cast<char*>(&Pbuf[w * 512]);

  for (int s0 = 0; s0 < L_; s0 += 32) {
    short8 kA0 = *reinterpret_cast<const short8*>(&kb[(size_t)(s0 + llo) * E_ + lhi * 8]);
    short8 kA1 = *reinterpret_cast<const short8*>(&kb[(size_t)(s0 + 16 + llo) * E_ + lhi * 8]);
    f32x4 st0 = {}, st1 = {};
    st0 = mfma16(kA0, qB, st0);
    st1 = mfma16(kA1, qB, st1);

    float p[8];
    const bool far_hi = (lw0 - (s0 + 31)) >= 128;   // all l-s >= 128 -> dd=256
    const bool far_lo = (s0 - (lw0 + 15)) >= 128;   // all s-l >= 128 -> dd=0
    if (far_hi || far_lo) {
      const float qdc = far_hi ? qd256 : qd0;
      const u16* kcb = &kdc[far_hi ? 1024 : 0];
      u16x4 kc0 = *reinterpret_cast<const u16x4*>(&kcb[s0 + lhi * 4]);
      u16x4 kc1 = *reinterpret_cast<const u16x4*>(&kcb[s0 + 16 + lhi * 4]);
#pragma unroll
      for (int r = 0; r < 4; ++r) {
        p[r]     = __expf(st0[r] + qdc + bf2f(kc0[r]));
        p[4 + r] = __expf(st1[r] + qdc + bf2f(kc1[r]));
      }
    } else {
#pragma unroll
      for (int i = 0; i < 2; ++i)
#pragma unroll
        for (int r = 0; r < 4; ++r) {
          const int scol = s0 + i * 16 + lhi * 4 + r;
          int d = lg - scol;
          d = (d < -128 ? -128 : (d > 128 ? 128 : d)) + 128;
          float qd = bf2f(QDs[lrow * QDP + d]);
          float kd = bf2f(kdg[(size_t)scol * D_ + d]);
          p[i * 4 + r] = __expf((i ? st1[r] : st0[r]) + qd + kd);
        }
    }
    l_acc += ((p[0] + p[1]) + (p[2] + p[3])) + ((p[4] + p[5]) + (p[6] + p[7]));

    // pack P (bf16) into per-wave LDS, XOR-swizzled 8B units (even XOR keeps
    // k-order inside each 16B-aligned pair)
#pragma unroll
    for (int i = 0; i < 2; ++i)
#pragma unroll
      for (int b = 0; b < 2; ++b) {
        unsigned wv = (unsigned)f2bf(p[i * 4 + 2 * b]) |
                      ((unsigned)f2bf(p[i * 4 + 2 * b + 1]) << 16);
        int u = (i * 4 + lhi) ^ (llo & 6);
        *reinterpret_cast<unsigned*>(Pw + llo * 64 + u * 8 + b * 4) = wv;
      }
    short8 pB = *reinterpret_cast<const short8*>(
        Pw + llo * 64 + (((lhi * 2) ^ (llo & 6)) * 8));
    short8 vA0 = *reinterpret_cast<const short8*>(&vb[(size_t)llo * L_ + s0 + lhi * 8]);
    short8 vA1 = *reinterpret_cast<const short8*>(&vb[(size_t)(16 + llo) * L_ + s0 + lhi * 8]);
    o0 = mfma16(vA0, pB, o0);
    o1 = mfma16(vA1, pB, o1);
  }

  // row sum across the 4 lanes sharing llo (lane, lane^16, lane^32, lane^48)
  float l2 = l_acc + __shfl_xor(l_acc, 16);
  float lt = l2 + __shfl_xor(l2, 32);
  const float inv = 1.0f / lt;

  const int n = nh >> 5, h = nh & 31;
  const size_t obase = (((size_t)((n << 10) | lg)) * 32 + h) * 32;
  u16x4 w0, w1;
#pragma unroll
  for (int r = 0; r < 4; ++r) {
    w0[r] = f2bf(o0[r] * inv);
    w1[r] = f2bf(o1[r] * inv);
  }
  *reinterpret_cast<u16x4*>(&tb[obase + lhi * 4]) = w0;        // e = lhi*4+r
  *reinterpret_cast<u16x4*>(&tb[obase + 16 + lhi * 4]) = w1;   // e = 16+lhi*4+r
}

// ---- AddNorm 1: h = LN(t + x) -> bf16 ----
__global__ __launch_bounds__(256) void ln1_kernel(
    const u16* __restrict__ tbuf, const float* __restrict__ x,
    const float* __restrict__ g, const float* __restrict__ b,
    u16* __restrict__ hb) {
  __shared__ float red[8];
  const int row = blockIdx.x, tid = threadIdx.x;
  const size_t base = (size_t)row * C_ + tid * 4;
  f32x4 xv = *reinterpret_cast<const f32x4*>(&x[base]);
  u16x4 tv = *reinterpret_cast<const u16x4*>(&tbuf[base]);
  float v[4]; float s1 = 0.f, s2 = 0.f;
#pragma unroll
  for (int i = 0; i < 4; ++i) {
    v[i] = xv[i] + bf2f(tv[i]);
    s1 += v[i]; s2 += v[i] * v[i];
  }
#pragma unroll
  for (int off = 32; off >= 1; off >>= 1) {
    s1 += __shfl_xor(s1, off); s2 += __shfl_xor(s2, off);
  }
  if ((tid & 63) == 0) { red[tid >> 6] = s1; red[4 + (tid >> 6)] = s2; }
  __syncthreads();
  float S1 = red[0] + red[1] + red[2] + red[3];
  float S2 = red[4] + red[5] + red[6] + red[7];
  float mu = S1 * (1.f / C_);
  float rs = rsqrtf(S2 * (1.f / C_) - mu * mu + 1e-5f);
#pragma unroll
  for (int i = 0; i < 4; ++i) {
    int c = tid * 4 + i;
    hb[base + i] = f2bf((v[i] - mu) * rs * g[c] + b[c]);
  }
}

// ---- AddNorm 2: out = LN(m + h) -> fp32, transposed (L, N, C) ----
__global__ __launch_bounds__(256) void ln2_kernel(
    const u16* __restrict__ mb, const u16* __restrict__ hb,
    const float* __restrict__ g, const float* __restrict__ b,
    float* __restrict__ out) {
  __shared__ float red[8];
  const int row = blockIdx.x, tid = threadIdx.x;
  const size_t base = (size_t)row * C_ + tid * 4;
  u16x4 mv = *reinterpret_cast<const u16x4*>(&mb[base]);
  u16x4 hv = *reinterpret_cast<const u16x4*>(&hb[base]);
  float v[4]; float s1 = 0.f, s2 = 0.f;
#pragma unroll
  for (int i = 0; i < 4; ++i) {
    v[i] = bf2f(mv[i]) + bf2f(hv[i]);
    s1 += v[i]; s2 += v[i] * v[i];
  }
#pragma unroll
  for (int off = 32; off >= 1; off >>= 1) {
    s1 += __shfl_xor(s1, off); s2 += __shfl_xor(s2, off);
  }
  if ((tid & 63) == 0) { red[tid >> 6] = s1; red[4 + (tid >> 6)] = s2; }
  __syncthreads();
  float S1 = red[0] + red[1] + red[2] + red[3];
  float S2 = red[4] + red[5] + red[6] + red[7];
  float mu = S1 * (1.f / C_);
  float rs = rsqrtf(S2 * (1.f / C_) - mu * mu + 1e-5f);
  const int n = row >> 10, l = row & 1023;
  const size_t ob = (size_t)(l * N_ + n) * C_ + tid * 4;
#pragma unroll
  for (int i = 0; i < 4; ++i) {
    int c = tid * 4 + i;
    out[ob + i] = (v[i] - mu) * rs * g[c] + b[c];
  }
}

extern "C" void kernel_launch(void* const* d_in, const int* in_sizes, int n_in,
                              void* d_out, int out_size, void* d_ws, size_t ws_size,
                              hipStream_t stream) {
  const float* x    = (const float*)d_in[0];
  const float* Wq   = (const float*)d_in[1];
  const float* bq   = (const float*)d_in[2];
  const float* Wk   = (const float*)d_in[3];
  const float* bk   = (const float*)d_in[4];
  const float* Wv   = (const float*)d_in[5];
  const float* bv   = (const float*)d_in[6];
  const float* demb = (const float*)d_in[7];
  const float* g1   = (const float*)d_in[8];
  const float* b1ln = (const float*)d_in[9];
  const float* g2   = (const float*)d_in[10];
  const float* b2ln = (const float*)d_in[11];
  const float* W1   = (const float*)d_in[12];
  const float* b1   = (const float*)d_in[13];
  const float* W2   = (const float*)d_in[14];
  const float* b2   = (const float*)d_in[15];
  float* outp = (float*)d_out;

  size_t o = 0;
  auto alloc = [&](size_t bytes) { size_t r = o; o += (bytes + 255) & ~(size_t)255; return r; };
  const size_t xb_o    = alloc((size_t)M_ * C_ * 2);
  const size_t wqkv_o  = alloc((size_t)3 * C_ * C_ * 2);
  const size_t w1_o    = alloc((size_t)C_ * C_ * 2);
  const size_t w2_o    = alloc((size_t)C_ * C_ * 2);
  const size_t bqkv_o  = alloc((size_t)3 * C_ * 4);
  const size_t demb_o  = alloc((size_t)D_ * E_ * 2);
  const size_t q_o     = alloc((size_t)NH_ * L_ * E_ * 2);
  const size_t k_o     = alloc((size_t)NH_ * L_ * E_ * 2);
  const size_t vt_o    = alloc((size_t)NH_ * L_ * E_ * 2);
  const size_t qd_o    = alloc((size_t)NH_ * L_ * QDP * 2);
  const size_t kd_o    = alloc((size_t)NH_ * L_ * D_ * 2);
  const size_t kd0_o   = alloc((size_t)NH_ * L_ * 2);
  const size_t kd256_o = alloc((size_t)NH_ * L_ * 2);
  const size_t t_o     = alloc((size_t)M_ * C_ * 2);
  const size_t h_o     = alloc((size_t)M_ * C_ * 2);
  const size_t m1_o    = alloc((size_t)M_ * C_ * 2);
  const size_t m_o     = alloc((size_t)M_ * C_ * 2);
  if (o > ws_size) return;  // ws too small -> visible zero-output failure

  char* ws = (char*)d_ws;
  u16*   xb     = (u16*)(ws + xb_o);
  u16*   wqkv_t = (u16*)(ws + wqkv_o);
  u16*   w1_t   = (u16*)(ws + w1_o);
  u16*   w2_t   = (u16*)(ws + w2_o);
  float* bqkv   = (float*)(ws + bqkv_o);
  u16*   demb_b = (u16*)(ws + demb_o);
  u16*   q_ws   = (u16*)(ws + q_o);
  u16*   k_ws   = (u16*)(ws + k_o);
  u16*   vT_ws  = (u16*)(ws + vt_o);
  u16*   QD     = (u16*)(ws + qd_o);
  u16*   KD     = (u16*)(ws + kd_o);
  u16*   kd0a   = (u16*)(ws + kd0_o);
  u16*   kd256a = (u16*)(ws + kd256_o);
  u16*   t_b16  = (u16*)(ws + t_o);
  u16*   h_b16  = (u16*)(ws + h_o);
  u16*   m1_b16 = (u16*)(ws + m1_o);
  u16*   m_b16  = (u16*)(ws + m_o);

  prep_kernel<<<33, 256, 0, stream>>>(demb, bq, bk, bv, demb_b, bqkv);
  cvt_x_kernel<<<(M_ * C_) / 1024, 256, 0, stream>>>(x, xb);
  dim3 tb_(32, 8), tg_(32, 32);
  transpose_w_kernel<<<tg_, tb_, 0, stream>>>(Wq, wqkv_t);
  transpose_w_kernel<<<tg_, tb_, 0, stream>>>(Wk, wqkv_t + (size_t)C_ * C_);
  transpose_w_kernel<<<tg_, tb_, 0, stream>>>(Wv, wqkv_t + (size_t)2 * C_ * C_);
  transpose_w_kernel<<<tg_, tb_, 0, stream>>>(W1, w1_t);
  transpose_w_kernel<<<tg_, tb_, 0, stream>>>(W2, w2_t);

  gemm128_kernel<0><<<32 * 24, 256, 0, stream>>>(xb, wqkv_t, C_, bqkv, q_ws, k_ws, vT_ws);

  // QD from temp-scaled q (scale folded already); KD needs explicit temp scale
  qdkd_kernel<<<2048, 256, 0, stream>>>(q_ws, demb_b, QD, QDP, 1.0f, nullptr, nullptr);
  qdkd_kernel<<<2048, 256, 0, stream>>>(k_ws, demb_b, KD, D_, TEMP_, kd0a, kd256a);

  attn_kernel<<<NH_ * 16, 256, 0, stream>>>(q_ws, k_ws, vT_ws, QD, KD, kd0a, kd256a, t_b16);

  ln1_kernel<<<M_, 256, 0, stream>>>(t_b16, x, g1, b1ln, h_b16);

  gemm128_kernel<1><<<32 * 8, 256, 0, stream>>>(h_b16, w1_t, C_, b1, m1_b16, nullptr, nullptr);
  gemm128_kernel<2><<<32 * 8, 256, 0, stream>>>(m1_b16, w2_t, C_, b2, m_b16, nullptr, nullptr);

  ln2_kernel<<<M_, 256, 0, stream>>>(m_b16, h_b16, g2, b2ln, outp);
}